// Round 9
// baseline (151.800 us; speedup 1.0000x reference)
//
#include <hip/hip_runtime.h>
#include <stdint.h>
#include <stddef.h>

#define BB 16384
#define CC 500
#define DD 512
#define PADC 512
#define LMARGIN 1.0f
#define EPSQ 1e-12f
#define NK 16  // K-chunks of 32

typedef __attribute__((ext_vector_type(8))) _Float16 f16x8;
typedef __attribute__((ext_vector_type(4))) _Float16 f16x4;
typedef __attribute__((ext_vector_type(4))) float f32x4;

// ---- prepP: protos fp32 -> protoT f16 in FRAGMENT-LINEAR layout + p2 ----
// unit (cg, kc) at byte (cg*16 + kc)*1024; lane l's 16 B inside a unit =
// B[col = cg*16 + (l&15)][k = kc*32 + (l>>4)*8 .. +7].
__global__ void prepP_kernel(const float* __restrict__ protos,
                             unsigned short* __restrict__ protoT,
                             float* __restrict__ p2,
                             float* __restrict__ out) {
  __shared__ float s_arr[16][17];
  const int cg = blockIdx.x;   // 0..31
  const int t = threadIdx.x;   // 0..255
  const int colin = t & 15;
  const int jb = t >> 4;       // 0..15
  const int col = cg * 16 + colin;
  if (cg == 0 && t == 0) out[0] = 0.f;
  float s = 0.f;
#pragma unroll
  for (int u = 0; u < 4; ++u) {
    const int j8 = jb + u * 16;          // 0..63: 8-float k-unit
    const int kc = j8 >> 2, quad = j8 & 3;
    f32x4 a0 = {0.f, 0.f, 0.f, 0.f}, a1 = a0;
    if (col < CC) {
      const float* src = protos + (size_t)col * DD + j8 * 8;
      a0 = *(const f32x4*)src;
      a1 = *(const f32x4*)(src + 4);
    }
    f16x8 h;
#pragma unroll
    for (int uu = 0; uu < 4; ++uu) {
      h[uu] = (_Float16)a0[uu];
      h[uu + 4] = (_Float16)a1[uu];
      s = fmaf(a0[uu], a0[uu], s);
      s = fmaf(a1[uu], a1[uu], s);
    }
    *(f16x8*)(protoT + (size_t)(cg * 16 + kc) * 512 + (quad * 16 + colin) * 8) = h;
  }
  s_arr[colin][jb] = s;
  __syncthreads();
  if (t < 16) {
    float acc = 0.f;
#pragma unroll
    for (int i = 0; i < 16; ++i) acc += s_arr[t][i];
    p2[cg * 16 + t] = acc;
  }
}

// ---- main: 512 threads (8 waves); block = 64 rows x 512 cols; wave = all 64
// rows x 64-col octant; acc 4x4. A: fp32->f16 swizzled LDS in prologue.
// K-loop barrier-free; B fragment-linear global->VGPR ring-3 prefetch with
// per-block kc ROTATION (rot=(bid>>3)&15) to kill the XCD-L2 hotspot.
// LDS = exactly 64 KB; epilogue scratch aliased into Afull post-loop.
// rowBase uses bid&255 so a grid-1024 profiling clone does identical work. ----
__launch_bounds__(512, 2)
__global__ void main_kernel(const float* __restrict__ feat,
                            const unsigned short* __restrict__ protoT,
                            const float* __restrict__ p2,
                            const int* __restrict__ labels,
                            float* __restrict__ outp) {
  __shared__ __align__(16) unsigned char Afull[NK * 4096];  // 64 KB exactly
  float* redM = (float*)&Afull[0];     // [64 rows][8 w]   (aliased, post-loop)
  float* redP = (float*)&Afull[2048];  // [64 rows][8 w]
  float* f2l = (float*)&Afull[4096];   // [64 rows]

  const int tid = threadIdx.x;
  const int w = tid >> 6;
  const int lane = tid & 63;
  const int lane16 = lane & 15;
  const int quad = lane >> 4;
  const int r0 = (blockIdx.x & 255) * 64;
  const int rot = (blockIdx.x >> 3) & 15;  // 16-way kc stagger within an XCD

  // ---- B pointers: unit (w*64 + nt*16 cols, kc) at byte (cg*16+kc)*1024 ----
  const char* bptr[4];
#pragma unroll
  for (int nt = 0; nt < 4; ++nt)
    bptr[nt] = (const char*)protoT + (size_t)(w * 64 + nt * 16) * 1024 + lane * 16;

  // issue B(kc=0), B(kc=1) early (rotated; retire during the A prologue)
  f16x8 bfr[3][4];
#pragma unroll
  for (int nt = 0; nt < 4; ++nt) {
    bfr[0][nt] = *(const f16x8*)(bptr[nt] + (size_t)rot * 1024);
    bfr[1][nt] = *(const f16x8*)(bptr[nt] + (size_t)((rot + 1) & 15) * 1024);
  }

  // ---- A prologue: thread (arow = tid>>3, aj = tid&7); 2 batches of 8 ----
  const int arow = tid >> 3;
  const int aj = tid & 7;
  const float* aSrc = feat + (size_t)(r0 + arow) * DD + aj * 4;
  const int awbase =
      arow * 64 + (((aj >> 1) ^ ((arow >> 1) & 3)) * 16) + (aj & 1) * 8;

  float s = 0.f;
#pragma unroll
  for (int p = 0; p < 2; ++p) {
    f32x4 av[8];
#pragma unroll
    for (int i = 0; i < 8; ++i)
      av[i] = *(const f32x4*)(aSrc + (p * 8 + i) * 32);
#pragma unroll
    for (int i = 0; i < 8; ++i) {
      f16x4 h;
#pragma unroll
      for (int u = 0; u < 4; ++u) {
        h[u] = (_Float16)av[i][u];
        s = fmaf(av[i][u], av[i][u], s);
      }
      *(f16x4*)(&Afull[(p * 8 + i) * 4096 + awbase]) = h;
    }
  }
  // f2 for row arow: 8 consecutive lanes share it (stays in a register
  // through the K-loop; written to aliased LDS after barrier #2)
  s += __shfl_xor(s, 1, 64);
  s += __shfl_xor(s, 2, 64);
  s += __shfl_xor(s, 4, 64);

  f32x4 acc[4][4];
#pragma unroll
  for (int mt = 0; mt < 4; ++mt)
#pragma unroll
    for (int nt = 0; nt < 4; ++nt) acc[mt][nt] = (f32x4){0.f, 0.f, 0.f, 0.f};

  __syncthreads();  // barrier #1: A tile staged

  // ---- K-loop: no barriers, no LDS writes; rotated B ring-3/depth-2 ----
  const int aroff = lane16 * 64 + ((quad ^ ((lane16 >> 1) & 3)) * 16);
#pragma unroll
  for (int kc = 0; kc < NK; ++kc) {
    const int kr = (kc + rot) & 15;
    if (kc + 2 < NK) {
      const int kp = (kc + 2 + rot) & 15;
#pragma unroll
      for (int nt = 0; nt < 4; ++nt)
        bfr[(kc + 2) % 3][nt] = *(const f16x8*)(bptr[nt] + (size_t)kp * 1024);
    }
    f16x8 af[4];
#pragma unroll
    for (int mt = 0; mt < 4; ++mt)
      af[mt] = *(const f16x8*)(&Afull[kr * 4096 + mt * 1024 + aroff]);
#pragma unroll
    for (int mt = 0; mt < 4; ++mt)
#pragma unroll
      for (int nt = 0; nt < 4; ++nt)
        acc[mt][nt] = __builtin_amdgcn_mfma_f32_16x16x32_f16(
            af[mt], bfr[kc % 3][nt], acc[mt][nt], 0, 0, 0);
  }

  __syncthreads();  // barrier #2: all waves done reading Afull -> alias safe

  if ((lane & 7) == 0) f2l[arow] = s;

  // ---- epilogue: q = p2 - 2*dot; masked min/pos over my 64 cols ----
  float p2v[4];
#pragma unroll
  for (int nt = 0; nt < 4; ++nt) p2v[nt] = p2[w * 64 + nt * 16 + lane16];

#pragma unroll
  for (int mt = 0; mt < 4; ++mt) {
#pragma unroll
    for (int i = 0; i < 4; ++i) {
      const int row = mt * 16 + quad * 4 + i;
      const int lb = labels[r0 + row];  // wave-uniform broadcast
      float qm = 1e30f, qp = -1e30f;
#pragma unroll
      for (int nt = 0; nt < 4; ++nt) {
        const int col = w * 64 + nt * 16 + lane16;
        float q = p2v[nt] - 2.f * acc[mt][nt][i];
        bool isPos = (col == lb);
        qp = fmaxf(qp, isPos ? q : -1e30f);
        qm = fminf(qm, (!isPos && col < CC) ? q : 1e30f);
      }
#pragma unroll
      for (int d = 1; d < 16; d <<= 1) {
        qm = fminf(qm, __shfl_xor(qm, d, 64));
        qp = fmaxf(qp, __shfl_xor(qp, d, 64));
      }
      if (lane16 == 0) {
        redM[row * 8 + w] = qm;
        redP[row * 8 + w] = qp;
      }
    }
  }
  __syncthreads();  // barrier #3: partials + f2l visible

  // ---- combine 8 octants per row, sqrt+hinge, block sum, one atomic ----
  if (tid < 64) {
    float qm = 1e30f, qp = -1e30f;
#pragma unroll
    for (int j = 0; j < 8; ++j) {
      qm = fminf(qm, redM[tid * 8 + j]);
      qp = fmaxf(qp, redP[tid * 8 + j]);
    }
    float f2 = f2l[tid];
    float dn = sqrtf(fmaxf(f2 + qm, EPSQ));
    float dp = sqrtf(fmaxf(f2 + qp, EPSQ));
    float term = fmaxf(dp - dn + LMARGIN, 0.f);
#pragma unroll
    for (int d = 1; d < 64; d <<= 1) term += __shfl_xor(term, d, 64);
    if (tid == 0) atomicAdd(outp, term * (1.0f / BB));
  }
}

extern "C" void kernel_launch(void* const* d_in, const int* in_sizes, int n_in,
                              void* d_out, int out_size, void* d_ws, size_t ws_size,
                              hipStream_t stream) {
  const float* feat = (const float*)d_in[0];
  const float* protos = (const float*)d_in[1];
  const int* labels = (const int*)d_in[2];
  float* out = (float*)d_out;

  char* ws = (char*)d_ws;
  unsigned short* protoT = (unsigned short*)(ws);   // 512 KB fragment-linear B
  float* p2 = (float*)(ws + (512 << 10));           // 2 KB
  float* dummy = (float*)(ws + (528 << 10));        // profiling sink

  prepP_kernel<<<32, 256, 0, stream>>>(protos, protoT, p2, out);
  // real dispatch (result)
  main_kernel<<<256, 512, 0, stream>>>(feat, protoT, p2, labels, out);
  // INSTRUMENTATION (this round only): 4x-work clone into a dummy sink so the
  // kernel rises into rocprof's top-5 with full counters at 2 blocks/CU.
  main_kernel<<<1024, 512, 0, stream>>>(feat, protoT, p2, labels, dummy);
}

// Round 10
// 93.606 us; speedup vs baseline: 1.6217x; 1.6217x over previous
//
#include <hip/hip_runtime.h>
#include <stdint.h>
#include <stddef.h>

#define BB 16384
#define CC 500
#define DD 512
#define PADC 512
#define LMARGIN 1.0f
#define EPSQ 1e-12f
#define NK 16    // K-chunks of 32
#define ROWS 32  // rows per block

typedef __attribute__((ext_vector_type(8))) _Float16 f16x8;
typedef __attribute__((ext_vector_type(4))) _Float16 f16x4;
typedef __attribute__((ext_vector_type(4))) float f32x4;

// ---- prepP: protos fp32 -> protoT f16 in FRAGMENT-LINEAR layout + p2 ----
// unit (cg, kc) at byte (cg*16 + kc)*1024; lane l's 16 B inside a unit =
// B[col = cg*16 + (l&15)][k = kc*32 + (l>>4)*8 .. +7].
__global__ void prepP_kernel(const float* __restrict__ protos,
                             unsigned short* __restrict__ protoT,
                             float* __restrict__ p2,
                             float* __restrict__ out) {
  __shared__ float s_arr[16][17];
  const int cg = blockIdx.x;   // 0..31
  const int t = threadIdx.x;   // 0..255
  const int colin = t & 15;
  const int jb = t >> 4;       // 0..15
  const int col = cg * 16 + colin;
  if (cg == 0 && t == 0) out[0] = 0.f;
  float s = 0.f;
#pragma unroll
  for (int u = 0; u < 4; ++u) {
    const int j8 = jb + u * 16;          // 0..63: 8-float k-unit
    const int kc = j8 >> 2, quad = j8 & 3;
    f32x4 a0 = {0.f, 0.f, 0.f, 0.f}, a1 = a0;
    if (col < CC) {
      const float* src = protos + (size_t)col * DD + j8 * 8;
      a0 = *(const f32x4*)src;
      a1 = *(const f32x4*)(src + 4);
    }
    f16x8 h;
#pragma unroll
    for (int uu = 0; uu < 4; ++uu) {
      h[uu] = (_Float16)a0[uu];
      h[uu + 4] = (_Float16)a1[uu];
      s = fmaf(a0[uu], a0[uu], s);
      s = fmaf(a1[uu], a1[uu], s);
    }
    *(f16x8*)(protoT + (size_t)(cg * 16 + kc) * 512 + (quad * 16 + colin) * 8) = h;
  }
  s_arr[colin][jb] = s;
  __syncthreads();
  if (t < 16) {
    float acc = 0.f;
#pragma unroll
    for (int i = 0; i < 16; ++i) acc += s_arr[t][i];
    p2[cg * 16 + t] = acc;
  }
}

// ---- main: 512 blocks x 512 threads (8 waves); block = 32 rows x 512 cols;
// wave = all 32 rows x 64-col octant; acc 2x4 of 16x16x32.
// LDS = 32 KB -> 2 blocks/CU co-resident (16 waves/CU, the R9-clone-measured
// sweet spot; cross-block overlap hides the A prologue + K-loop latency).
// A: fp32->f16 XOR-swizzled LDS in prologue. K-loop barrier-free; B
// fragment-linear global->VGPR ring-3/depth-2 with per-block kc rotation.
// Hinge completes in-block; 3 barriers total. ----
__launch_bounds__(512, 4)
__global__ void main_kernel(const float* __restrict__ feat,
                            const unsigned short* __restrict__ protoT,
                            const float* __restrict__ p2,
                            const int* __restrict__ labels,
                            float* __restrict__ outp) {
  __shared__ __align__(16) unsigned char Afull[NK * 2048];  // 32 KB exactly
  float* redM = (float*)&Afull[0];     // [32 rows][8 w] = 1 KB (aliased)
  float* redP = (float*)&Afull[1024];  // [32 rows][8 w]
  float* f2l = (float*)&Afull[2048];   // [32 rows]

  const int tid = threadIdx.x;
  const int w = tid >> 6;
  const int lane = tid & 63;
  const int lane16 = lane & 15;
  const int quad = lane >> 4;
  const int r0 = blockIdx.x * ROWS;
  const int rot = (blockIdx.x >> 3) & 15;  // kc stagger to spread L2 traffic

  // ---- B pointers: unit (cg = w*4+nt, kc) at byte (cg*16+kc)*1024 ----
  const char* bptr[4];
#pragma unroll
  for (int nt = 0; nt < 4; ++nt)
    bptr[nt] = (const char*)protoT + (size_t)(w * 64 + nt * 16) * 1024 + lane * 16;

  // issue B(kc=rot), B(rot+1) early (retire during the A prologue)
  f16x8 bfr[3][4];
#pragma unroll
  for (int nt = 0; nt < 4; ++nt) {
    bfr[0][nt] = *(const f16x8*)(bptr[nt] + (size_t)rot * 1024);
    bfr[1][nt] = *(const f16x8*)(bptr[nt] + (size_t)((rot + 1) & 15) * 1024);
  }

  // ---- A prologue: thread (arow = tid>>4, aj = tid&15) stages 8 f32x4:
  // chunk i at k = aj*4 + i*64 -> kc = 2i + (aj>>3), within-kc off (aj&7)*4 ----
  const int arow = tid >> 4;  // 0..31
  const int aj = tid & 15;
  const int aj7 = aj & 7, ajh = aj >> 3;
  const float* aSrc = feat + (size_t)(r0 + arow) * DD + aj * 4;
  const int awbase =
      arow * 64 + (((aj7 >> 1) ^ ((arow >> 1) & 3)) * 16) + (aj7 & 1) * 8;

  float s = 0.f;
  {
    f32x4 av[8];
#pragma unroll
    for (int i = 0; i < 8; ++i) av[i] = *(const f32x4*)(aSrc + i * 64);
#pragma unroll
    for (int i = 0; i < 8; ++i) {
      f16x4 h;
#pragma unroll
      for (int u = 0; u < 4; ++u) {
        h[u] = (_Float16)av[i][u];
        s = fmaf(av[i][u], av[i][u], s);
      }
      *(f16x4*)(&Afull[(2 * i + ajh) * 2048 + awbase]) = h;
    }
  }
  // f2 for row arow: 16 consecutive lanes share it (held in a register)
  s += __shfl_xor(s, 1, 64);
  s += __shfl_xor(s, 2, 64);
  s += __shfl_xor(s, 4, 64);
  s += __shfl_xor(s, 8, 64);

  f32x4 acc[2][4];
#pragma unroll
  for (int mt = 0; mt < 2; ++mt)
#pragma unroll
    for (int nt = 0; nt < 4; ++nt) acc[mt][nt] = (f32x4){0.f, 0.f, 0.f, 0.f};

  __syncthreads();  // barrier #1: A tile staged

  // ---- K-loop: no barriers, no LDS writes; rotated B ring-3/depth-2 ----
  const int aroff = lane16 * 64 + ((quad ^ ((lane16 >> 1) & 3)) * 16);
#pragma unroll
  for (int kc = 0; kc < NK; ++kc) {
    const int kr = (kc + rot) & 15;
    if (kc + 2 < NK) {
      const int kp = (kc + 2 + rot) & 15;
#pragma unroll
      for (int nt = 0; nt < 4; ++nt)
        bfr[(kc + 2) % 3][nt] = *(const f16x8*)(bptr[nt] + (size_t)kp * 1024);
    }
    f16x8 af[2];
#pragma unroll
    for (int mt = 0; mt < 2; ++mt)
      af[mt] = *(const f16x8*)(&Afull[kr * 2048 + mt * 1024 + aroff]);
#pragma unroll
    for (int mt = 0; mt < 2; ++mt)
#pragma unroll
      for (int nt = 0; nt < 4; ++nt)
        acc[mt][nt] = __builtin_amdgcn_mfma_f32_16x16x32_f16(
            af[mt], bfr[kc % 3][nt], acc[mt][nt], 0, 0, 0);
  }

  __syncthreads();  // barrier #2: all waves done reading Afull -> alias safe

  if ((tid & 15) == 0) f2l[arow] = s;

  // ---- epilogue: q = p2 - 2*dot; masked min/pos over my 64 cols ----
  float p2v[4];
#pragma unroll
  for (int nt = 0; nt < 4; ++nt) p2v[nt] = p2[w * 64 + nt * 16 + lane16];

#pragma unroll
  for (int mt = 0; mt < 2; ++mt) {
#pragma unroll
    for (int i = 0; i < 4; ++i) {
      const int row = mt * 16 + quad * 4 + i;
      const int lb = labels[r0 + row];  // wave-uniform broadcast
      float qm = 1e30f, qp = -1e30f;
#pragma unroll
      for (int nt = 0; nt < 4; ++nt) {
        const int col = w * 64 + nt * 16 + lane16;
        float q = p2v[nt] - 2.f * acc[mt][nt][i];
        bool isPos = (col == lb);
        qp = fmaxf(qp, isPos ? q : -1e30f);
        qm = fminf(qm, (!isPos && col < CC) ? q : 1e30f);
      }
#pragma unroll
      for (int d = 1; d < 16; d <<= 1) {
        qm = fminf(qm, __shfl_xor(qm, d, 64));
        qp = fmaxf(qp, __shfl_xor(qp, d, 64));
      }
      if (lane16 == 0) {
        redM[row * 8 + w] = qm;
        redP[row * 8 + w] = qp;
      }
    }
  }
  __syncthreads();  // barrier #3: partials + f2l visible

  // ---- combine 8 octants per row, sqrt+hinge, block sum, one atomic ----
  if (tid < ROWS) {
    float qm = 1e30f, qp = -1e30f;
#pragma unroll
    for (int j = 0; j < 8; ++j) {
      qm = fminf(qm, redM[tid * 8 + j]);
      qp = fmaxf(qp, redP[tid * 8 + j]);
    }
    float f2 = f2l[tid];
    float dn = sqrtf(fmaxf(f2 + qm, EPSQ));
    float dp = sqrtf(fmaxf(f2 + qp, EPSQ));
    float term = fmaxf(dp - dn + LMARGIN, 0.f);
#pragma unroll
    for (int d = 1; d < 32; d <<= 1) term += __shfl_xor(term, d, 64);
    if (tid == 0) atomicAdd(outp, term * (1.0f / BB));
  }
}

extern "C" void kernel_launch(void* const* d_in, const int* in_sizes, int n_in,
                              void* d_out, int out_size, void* d_ws, size_t ws_size,
                              hipStream_t stream) {
  const float* feat = (const float*)d_in[0];
  const float* protos = (const float*)d_in[1];
  const int* labels = (const int*)d_in[2];
  float* out = (float*)d_out;

  char* ws = (char*)d_ws;
  unsigned short* protoT = (unsigned short*)(ws);   // 512 KB fragment-linear B
  float* p2 = (float*)(ws + (512 << 10));           // 2 KB

  prepP_kernel<<<32, 256, 0, stream>>>(protos, protoT, p2, out);
  main_kernel<<<BB / ROWS, 512, 0, stream>>>(feat, protoT, p2, labels, out);
}